// Round 6
// baseline (2304.886 us; speedup 1.0000x reference)
//
#include <hip/hip_runtime.h>

typedef _Float16 f16;
typedef _Float16 f16x8 __attribute__((ext_vector_type(8)));
typedef _Float16 f16x4 __attribute__((ext_vector_type(4)));
typedef float    f32x4 __attribute__((ext_vector_type(4)));

#define NP      82944     // 4*144*144 pixels
#define NPIX_B  20736     // 144*144
#define KP      320       // padded channel dim (300 -> 320)
#define OC      128       // 2*HID
#define NP2     80656     // 4*142*142 head pixels
#define NOC     15        // encoder o-chunks
#define OCH     20        // outputs per o-chunk (15*20 = 300)
#define GN      192       // gate: pixels per block (chpx % 192 == 0 for CH=4,8)
#define GBUF    24576     // gate: bytes per LDS buffer (1536 chunks x 16B)

__device__ __forceinline__ float geluf(float x) {
    return 0.5f * x * (1.0f + erff(x * 0.70710678118654752f));
}
__device__ __forceinline__ float sigm(float x) {
    return 1.0f / (1.0f + __expf(-x));
}
__device__ __forceinline__ f32x4 mfma16(f16x8 a, f16x8 b, f32x4 c) {
    return __builtin_amdgcn_mfma_f32_16x16x32_f16(a, b, c, 0, 0, 0);
}
__device__ __forceinline__ void gload_lds16(const void* g, void* l) {
    __builtin_amdgcn_global_load_lds(
        (const __attribute__((address_space(1))) void*)g,
        (__attribute__((address_space(3))) void*)l, 16, 0, 0);
}
// bijective XCD-chunked remap (m204)
__device__ __forceinline__ int xcd_swz(int bid, int nwg) {
    int q = nwg >> 3, r = nwg & 7;
    int xcd = bid & 7, idx = bid >> 3;
    return (xcd < r ? xcd * (q + 1) : r * (q + 1) + (xcd - r) * q) + idx;
}

// ---------------- weight packing ----------------
__global__ __launch_bounds__(64) void pack_gate_w(
    const float* __restrict__ wd2, const float* __restrict__ wfx2, const float* __restrict__ wix2,
    const float* __restrict__ wd1, const float* __restrict__ wfx1, const float* __restrict__ wix1,
    const float* __restrict__ bd2, const float* __restrict__ bfx2, const float* __restrict__ bix2,
    const float* __restrict__ bd1, const float* __restrict__ bfx1, const float* __restrict__ bix1,
    f16* __restrict__ wpk2, f16* __restrict__ wpk1,
    float* __restrict__ bpk2, float* __restrict__ bpk1)
{
    int bid = blockIdx.x;                 // [0, 2*3*320)
    int o = bid % KP;
    int g = (bid / KP) % 3;
    int s = bid / (KP * 3);
    const float* wsrc; const float* bsrc;
    if (s == 0) { wsrc = (g==0)?wd2:((g==1)?wfx2:wix2); bsrc = (g==0)?bd2:((g==1)?bfx2:bix2); }
    else        { wsrc = (g==0)?wd1:((g==1)?wfx1:wix1); bsrc = (g==0)?bd1:((g==1)?bfx1:bix1); }
    f16* wdst = (s==0 ? wpk2 : wpk1) + ((size_t)g*KP + o)*KP;
    int t = threadIdx.x;
#pragma unroll
    for (int i = 0; i < 5; ++i) {
        int k = i*64 + t;
        wdst[k] = (o < 300 && k < 300) ? (f16)wsrc[o*300 + k] : (f16)0.0f;
    }
    if (t == 0) {
        float* bd = (s==0 ? bpk2 : bpk1);
        bd[g*KP + o] = (o < 300) ? bsrc[o] : 0.0f;
    }
}

__global__ __launch_bounds__(64) void pack_line_w(
    const float* __restrict__ lw1, const float* __restrict__ lw2,
    f16* __restrict__ w1p, f16* __restrict__ w2p)
{
    int bid = blockIdx.x;
    int t = threadIdx.x;
    if (bid < 9*OC) {
        int t9 = bid / OC, oc = bid % OC;
        f16* dst = w1p + ((size_t)t9*OC + oc)*KP;
#pragma unroll
        for (int i = 0; i < 5; ++i) {
            int k = i*64 + t;
            dst[k] = (k < 300) ? (f16)lw1[(size_t)(oc*300 + k)*9 + t9] : (f16)0.0f;
        }
    } else {
        int oc = bid - 9*OC;
        f16* dst = w2p + (size_t)oc*OC;
#pragma unroll
        for (int i = 0; i < 2; ++i) {
            int k = i*64 + t;
            dst[k] = (f16)lw2[oc*OC + k];
        }
    }
}

// ---------------- encoder (per chunk, o-split) ----------------
__global__ __launch_bounds__(256) void encoder_kernel(
    const float* __restrict__ y,
    const float* __restrict__ w_e1, const float* __restrict__ b_e1,
    const float* __restrict__ w_e2, const float* __restrict__ b_e2,
    const float* __restrict__ w_f1, const float* __restrict__ b_f1,
    const float* __restrict__ w_i1, const float* __restrict__ b_i1,
    const float* __restrict__ w_f2, const float* __restrict__ b_f2,
    const float* __restrict__ w_i2, const float* __restrict__ b_i2,
    f16* __restrict__ enc, float* __restrict__ cbuf, f16* __restrict__ xa,
    int p_off, int chpx)
{
    int lid = xcd_swz(blockIdx.x, gridDim.x);
    int oc = lid % NOC;
    int pb = lid / NOC;
    int p  = pb * 256 + threadIdx.x;
    if (p >= chpx) return;
    int o0 = oc * OCH;
    int gp = p_off + p;
    int b = gp / NPIX_B, pin = gp % NPIX_B;
    const float* yb = y + (size_t)b*21*NPIX_B + pin;
    float yv[21];
#pragma unroll
    for (int c = 0; c < 21; ++c) yv[c] = yb[(size_t)c * NPIX_B];

    size_t rowbase = (size_t)p*KP + o0;
    size_t estr = (size_t)chpx*KP;

#define ENC_ONE(W, B, EIDX)                                            \
    {                                                                  \
        f16* dst = enc + (size_t)(EIDX)*estr + rowbase;                \
        _Pragma("unroll 1")                                            \
        for (int rq = 0; rq < 5; ++rq) {                               \
            f16x4 st;                                                  \
            _Pragma("unroll")                                          \
            for (int j = 0; j < 4; ++j) {                              \
                int r = rq*4 + j;                                      \
                const float* wr = (W) + (o0 + r)*21;                   \
                float acc = (B)[o0 + r];                               \
                _Pragma("unroll")                                      \
                for (int c = 0; c < 21; ++c) acc = fmaf(wr[c], yv[c], acc); \
                st[j] = (f16)geluf(acc);                               \
            }                                                          \
            *(f16x4*)(dst + rq*4) = st;                                \
        }                                                              \
    }

    ENC_ONE(w_e1, b_e1, 0)
    ENC_ONE(w_e2, b_e2, 1)
    ENC_ONE(w_f1, b_f1, 2)
    ENC_ONE(w_i1, b_i1, 3)
    ENC_ONE(w_f2, b_f2, 4)
    ENC_ONE(w_i2, b_i2, 5)
#undef ENC_ONE

#pragma unroll 1
    for (int rq = 0; rq < 5; ++rq) {
        f16x4 v0 = *(const f16x4*)(enc + (size_t)0*estr + rowbase + rq*4);
        f16x4 v3 = *(const f16x4*)(enc + (size_t)3*estr + rowbase + rq*4);
        f32x4 cv; f16x4 xv;
#pragma unroll
        for (int j = 0; j < 4; ++j) {
            float c12 = sigm((float)v3[j]) * (-(float)v0[j]);
            cv[j] = c12;
            xv[j] = (f16)fmaxf(c12, 0.0f);
        }
        *(f32x4*)(cbuf + rowbase + rq*4) = cv;
        *(f16x4*)(xa + rowbase + rq*4) = xv;
    }
}

// ---------------- fused gate half-step v3: counted-vmcnt pipeline ----------
// Tile: 96 A-rows (3 gates x 32 o) x 192 px, BK=32, 10 ksteps.
// LDS buf = 24576B: A 480 chunks (rows x 80B, slot4 dead), B 960 chunks,
// pad 96 chunks (dead). Every thread stages exactly 6 x 16B per k-step ->
// s_waitcnt vmcnt(6) retires tile k while tile k+1 stays in flight (T4).
__global__ __launch_bounds__(256) void gate_kernel(
    const f16* __restrict__ xin, const f16* __restrict__ wpk,
    const float* __restrict__ bpk,
    const f16* __restrict__ ey, const f16* __restrict__ fy,
    const f16* __restrict__ iy, const f16* __restrict__ ad,
    float* __restrict__ cio, f16* __restrict__ xout, int first, int chpx)
{
    __shared__ uint4 smem4[2*GBUF/16];
    char* smem = (char*)smem4;
    int tid = threadIdx.x;
    int l = tid & 63, w = tid >> 6;
    int lr = l & 15, lh = l >> 4;
    int lid = xcd_swz(blockIdx.x, gridDim.x);
    int mt = lid % 10, nt = lid / 10;
    int o0 = mt * 32;
    int p0 = nt * GN;

    // per-thread staging sources (k0=0); advance by 64B per kstep
    const char* srcb[6];
#pragma unroll
    for (int j = 0; j < 6; ++j) {
        int c = j*256 + tid;
        if (c < 480) {
            int row = c / 5, slot = c % 5; if (slot > 3) slot = 0;
            int g = row >> 5, o = o0 + (row & 31);
            srcb[j] = (const char*)wpk + ((size_t)g*KP + o)*(KP*2) + slot*16;
        } else if (c < 1440) {
            int cb = c - 480;
            int row = cb / 5, slot = cb % 5; if (slot > 3) slot = 0;
            srcb[j] = (const char*)xin + (size_t)(p0 + row)*(KP*2) + slot*16;
        } else {
            srcb[j] = (const char*)xin;   // dead chunk -> lands in pad region
        }
    }

#define GSTAGE(BUF, KS)                                                \
    {                                                                  \
        int kb = (KS)*64;                                              \
        _Pragma("unroll")                                              \
        for (int j = 0; j < 6; ++j)                                    \
            gload_lds16(srcb[j] + kb, &smem[(BUF)*GBUF + (j*256+tid)*16]); \
    }

    f32x4 acc[3][2][3] = {};
    GSTAGE(0, 0)

    int buf = 0;
#pragma unroll 1
    for (int ks = 0; ks < 10; ++ks) {
        if (ks < 9) {
            GSTAGE(buf^1, ks+1)
            asm volatile("s_waitcnt vmcnt(6)" ::: "memory");
        } else {
            asm volatile("s_waitcnt vmcnt(0)" ::: "memory");
        }
        __builtin_amdgcn_s_barrier();          // all waves' tile-ks staged
        f16x8 bfr[3];
#pragma unroll
        for (int n = 0; n < 3; ++n)
            bfr[n] = *(const f16x8*)&smem[buf*GBUF + 7680 + (w*48 + n*16 + lr)*80 + lh*16];
#pragma unroll
        for (int g = 0; g < 3; ++g) {
#pragma unroll
            for (int m = 0; m < 2; ++m) {
                f16x8 a = *(const f16x8*)&smem[buf*GBUF + (g*32 + m*16 + lr)*80 + lh*16];
#pragma unroll
                for (int n = 0; n < 3; ++n)
                    acc[g][m][n] = mfma16(a, bfr[n], acc[g][m][n]);
            }
        }
        if (ks < 9) __builtin_amdgcn_s_barrier();  // readers done before overwrite
        buf ^= 1;
    }
#undef GSTAGE

#pragma unroll
    for (int m = 0; m < 2; ++m) {
        int o = o0 + m*16 + lh*4;
        if (o >= 300) continue;
        f32x4 bd = *(const f32x4*)(bpk + 0*KP + o);
        f32x4 bf = *(const f32x4*)(bpk + 1*KP + o);
        f32x4 bi = *(const f32x4*)(bpk + 2*KP + o);
#pragma unroll
        for (int n = 0; n < 3; ++n) {
            int p = p0 + w*48 + n*16 + lr;
            if (p >= chpx) continue;
            size_t base = (size_t)p*KP + o;
            f16x4 vey = *(const f16x4*)(ey + base);
            f16x4 vfy = *(const f16x4*)(fy + base);
            f16x4 viy = *(const f16x4*)(iy + base);
            f32x4 vci = *(const f32x4*)(cio + base);
            f16x4 vad = {};
            if (!first) vad = *(const f16x4*)(ad + base);
            f32x4 co; f16x4 xo;
#pragma unroll
            for (int r = 0; r < 4; ++r) {
                float gd = geluf(acc[0][m][n][r] + bd[r]);
                float gf = geluf(acc[1][m][n][r] + bf[r]);
                float gi = geluf(acc[2][m][n][r] + bi[r]);
                float addv = first ? 0.0f : (float)vad[r];
                float ctl = (float)vey[r] + addv - gd;
                float ft  = sigm(gf + (float)vfy[r]);
                float it  = sigm(gi + (float)viy[r]);
                float ct  = vci[r]*ft + ctl*it;
                co[r] = ct;
                xo[r] = (f16)fmaxf(ct, 0.0f);
            }
            *(f32x4*)(cio + base) = co;
            *(f16x4*)(xout + base) = xo;
        }
    }
}

// ---------------- head: 3x3 valid conv v3 (k-streamed, reg-staged T14) -----
// Block: 128 oc x 48 out-px strip. LDS: one 12KB window (3 dy x 50 px rows,
// 80B stride, 16B aligned, 2-way banks), re-filled per k32 from registers;
// next tile's global loads issued right after the barrier (latency hides
// under 540 MFMA). A (w1p, L2-resident) read per-fragment from global.
__global__ __launch_bounds__(256) void conv3_kernel(
    const f16* __restrict__ xt, const f16* __restrict__ w1p,
    const float* __restrict__ b1, f16* __restrict__ h1)
{
    __shared__ uint4 smem4[750];   // 150 rows x 80B = 12000B
    char* smem = (char*)smem4;
    int tid = threadIdx.x;
    int l = tid & 63, w = tid >> 6;
    int lr = l & 15, lh = l >> 4;
    int lid = xcd_swz(blockIdx.x, gridDim.x);
    int xs = lid % 3;
    int by = lid / 3;               // [0, 568)
    int b = by / 142, yy = by % 142;
    int x0 = xs * 48;               // 0, 48, 96

    // staging map: 600 chunks (150 rows x 4 slots x 16B), <=3 per thread
    const char* sp[3];
    int dstb[3];
    bool act[3];
#pragma unroll
    for (int j = 0; j < 3; ++j) {
        int c = j*256 + tid;
        act[j] = (c < 600);
        int cc = act[j] ? c : 599;
        int row = cc >> 2, slot = cc & 3;
        int dy = row / 50, pxo = row % 50;
        int gx = x0 + pxo; if (gx > 143) gx = 143;
        size_t gp = (size_t)((b*144 + yy + dy)*144 + gx);
        sp[j] = (const char*)xt + gp*(KP*2) + slot*16;
        dstb[j] = row*80 + slot*16;
    }

    uint4 regs[3];
#pragma unroll
    for (int j = 0; j < 3; ++j) regs[j] = *(const uint4*)(sp[j]);   // tile k=0

    f32x4 acc[2][3] = {};
#pragma unroll 1
    for (int ks = 0; ks < 10; ++ks) {
        // write staged tile (compiler inserts vmcnt wait for reg deps)
#pragma unroll
        for (int j = 0; j < 3; ++j)
            if (act[j]) *(uint4*)&smem[dstb[j]] = regs[j];
        __syncthreads();
        if (ks < 9) {
            int kb = (ks+1)*64;
#pragma unroll
            for (int j = 0; j < 3; ++j) regs[j] = *(const uint4*)(sp[j] + kb);
        }
        int k0 = ks*32;
#pragma unroll 3
        for (int t9 = 0; t9 < 9; ++t9) {
            int dy = t9 / 3, dx = t9 % 3;
            const f16* ap = w1p + ((size_t)(t9*OC + w*32 + lr))*KP + k0 + lh*8;
            f16x8 a0 = *(const f16x8*)ap;
            f16x8 a1 = *(const f16x8*)(ap + (size_t)16*KP);
#pragma unroll
            for (int n = 0; n < 3; ++n) {
                int row = dy*50 + dx + n*16 + lr;
                f16x8 bv = *(const f16x8*)&smem[row*80 + lh*16];
                acc[0][n] = mfma16(a0, bv, acc[0][n]);
                acc[1][n] = mfma16(a1, bv, acc[1][n]);
            }
        }
        __syncthreads();               // readers done before next tile write
    }

#pragma unroll
    for (int m = 0; m < 2; ++m) {
        int ocb = w*32 + m*16 + lh*4;
        f32x4 bb = *(const f32x4*)(b1 + ocb);
#pragma unroll
        for (int n = 0; n < 3; ++n) {
            int x = x0 + n*16 + lr;
            if (x < 142) {
                int pout = (b*142 + yy)*142 + x;
                f16x4 hv;
#pragma unroll
                for (int r = 0; r < 4; ++r) hv[r] = (f16)geluf(acc[m][n][r] + bb[r]);
                *(f16x4*)(h1 + (size_t)pout*OC + ocb) = hv;
            }
        }
    }
}

// ---------------- head: 1x1 (128->128) + gelu ----------------
__global__ __launch_bounds__(256) void gemm128_kernel(
    const f16* __restrict__ hin, const f16* __restrict__ w2p,
    const float* __restrict__ b2, f16* __restrict__ hout)
{
    int tid = threadIdx.x;
    int l = tid & 63, w = tid >> 6;
    int lr = l & 15, lh = l >> 4;
    int bid = blockIdx.x;
    int mt = bid & 3, nt = bid >> 2;
    int p0 = nt * 128 + w * 32;
    if (p0 >= NP2) return;
    int o0 = mt * 32;

    f32x4 acc[2][2] = {};
    int pr0 = min(p0 + lr,      NP2 - 1);
    int pr1 = min(p0 + 16 + lr, NP2 - 1);
    const f16* bp0 = hin + (size_t)pr0*OC + lh*8;
    const f16* bp1 = hin + (size_t)pr1*OC + lh*8;
    const f16* ap  = w2p + (size_t)(o0 + lr)*OC + lh*8;
#pragma unroll
    for (int k0 = 0; k0 < OC; k0 += 32) {
        f16x8 b0  = *(const f16x8*)(bp0 + k0);
        f16x8 b1v = *(const f16x8*)(bp1 + k0);
#pragma unroll
        for (int m = 0; m < 2; ++m) {
            f16x8 a = *(const f16x8*)(ap + (size_t)m*16*OC + k0);
            acc[m][0] = mfma16(a, b0,  acc[m][0]);
            acc[m][1] = mfma16(a, b1v, acc[m][1]);
        }
    }
#pragma unroll
    for (int m = 0; m < 2; ++m) {
        int oc = o0 + m*16 + lh*4;
        f32x4 bb = *(const f32x4*)(b2 + oc);
#pragma unroll
        for (int n = 0; n < 2; ++n) {
            int p = p0 + n*16 + lr;
            if (p < NP2) {
                f16x4 hv;
#pragma unroll
                for (int r = 0; r < 4; ++r) hv[r] = (f16)geluf(acc[m][n][r] + bb[r]);
                *(f16x4*)(hout + (size_t)p*OC + oc) = hv;
            }
        }
    }
}

// ---------------- head: 1x1 (128->1) ----------------
__global__ __launch_bounds__(256) void final_dot_kernel(
    const f16* __restrict__ h2, const float* __restrict__ w3,
    const float* __restrict__ b3, float* __restrict__ out)
{
    int p = blockIdx.x * 256 + threadIdx.x;
    if (p >= NP2) return;
    const f16x8* row = (const f16x8*)(h2 + (size_t)p * OC);
    float acc = 0.0f;
#pragma unroll
    for (int i = 0; i < 16; ++i) {
        f16x8 v = row[i];
#pragma unroll
        for (int j = 0; j < 8; ++j) acc = fmaf((float)v[j], w3[i*8 + j], acc);
    }
    out[p] = acc + b3[0];
}

// ---------------- launch ----------------
extern "C" void kernel_launch(void* const* d_in, const int* in_sizes, int n_in,
                              void* d_out, int out_size, void* d_ws, size_t ws_size,
                              hipStream_t stream)
{
    const float* y      = (const float*)d_in[0];
    const float* we1_w  = (const float*)d_in[1];  const float* we1_b  = (const float*)d_in[2];
    const float* we2_w  = (const float*)d_in[3];  const float* we2_b  = (const float*)d_in[4];
    const float* wfy1_w = (const float*)d_in[5];  const float* wfy1_b = (const float*)d_in[6];
    const float* wiy1_w = (const float*)d_in[7];  const float* wiy1_b = (const float*)d_in[8];
    const float* wfy2_w = (const float*)d_in[9];  const float* wfy2_b = (const float*)d_in[10];
    const float* wiy2_w = (const float*)d_in[11]; const float* wiy2_b = (const float*)d_in[12];
    const float* wd1_w  = (const float*)d_in[13]; const float* wd1_b  = (const float*)d_in[14];
    const float* wd2_w  = (const float*)d_in[15]; const float* wd2_b  = (const float*)d_in[16];
    const float* wfx1_w = (const float*)d_in[17]; const float* wfx1_b = (const float*)d_in[18];
    const float* wix1_w = (const float*)d_in[19]; const float* wix1_b = (const float*)d_in[20];
    const float* wfx2_w = (const float*)d_in[21]; const float* wfx2_b = (const float*)d_in[22];
    const float* wix2_w = (const float*)d_in[23]; const float* wix2_b = (const float*)d_in[24];
    const float* line_w1 = (const float*)d_in[25]; const float* line_b1 = (const float*)d_in[26];
    const float* line_w2 = (const float*)d_in[27]; const float* line_b2 = (const float*)d_in[28];
    const float* line_w3 = (const float*)d_in[29]; const float* line_b3 = (const float*)d_in[30];
    float* out = (float*)d_out;

    auto padb = [](size_t b){ return (b + 255) & ~(size_t)255; };
    auto need = [&](int ch)->size_t {
        size_t chpx = (size_t)NP / ch;
        size_t s = 0;
        s += padb(6*chpx*KP*2);            // enc
        s += 2*padb(chpx*KP*2);            // xa, xb
        s += padb(chpx*KP*4);              // cbuf
        s += padb((size_t)NP*KP*2);        // xt1full
        s += 2*padb((size_t)3*KP*KP*2);    // wpk2, wpk1
        s += 2*padb((size_t)3*KP*4);       // bpk2, bpk1
        s += padb((size_t)9*OC*KP*2);      // w1p
        s += padb((size_t)OC*OC*2);        // w2p
        return s;
    };
    const int CHN = (need(4) <= ws_size) ? 4 : 8;
    const int chpx = NP / CHN;

    char* base = (char*)d_ws;
    size_t off = 0;
    auto take = [&](size_t bytes) -> void* {
        void* r = base + off;
        off += (bytes + 255) & ~(size_t)255;
        return r;
    };
    char* chunk_base = base;
    f16*   enc  = (f16*)take((size_t)6 * chpx * KP * sizeof(f16));
    f16*   xa   = (f16*)take((size_t)chpx * KP * sizeof(f16));
    f16*   xb   = (f16*)take((size_t)chpx * KP * sizeof(f16));
    float* cbuf = (float*)take((size_t)chpx * KP * sizeof(float));
    f16* xt1full = (f16*)take((size_t)NP * KP * sizeof(f16));
    f16* wpk2 = (f16*)take((size_t)3 * KP * KP * sizeof(f16));
    f16* wpk1 = (f16*)take((size_t)3 * KP * KP * sizeof(f16));
    float* bpk2 = (float*)take((size_t)3 * KP * sizeof(float));
    float* bpk1 = (float*)take((size_t)3 * KP * sizeof(float));
    f16* w1p = (f16*)take((size_t)9 * OC * KP * sizeof(f16));
    f16* w2p = (f16*)take((size_t)OC * OC * sizeof(f16));
    f16* h1 = (f16*)chunk_base;   // alias dead chunk region for the head
    f16* h2 = (f16*)(chunk_base + (size_t)NP2 * OC * sizeof(f16));
    if (off > ws_size) return;    // fail loudly via absmax

    pack_gate_w<<<2*3*KP, 64, 0, stream>>>(wd2_w, wfx2_w, wix2_w, wd1_w, wfx1_w, wix1_w,
                                           wd2_b, wfx2_b, wix2_b, wd1_b, wfx1_b, wix1_b,
                                           wpk2, wpk1, bpk2, bpk1);
    pack_line_w<<<9*OC + OC, 64, 0, stream>>>(line_w1, line_w2, w1p, w2p);

    const int EGRID = ((chpx + 255) / 256) * NOC;
    const int GGRID = (chpx / GN) * 10;
    f16* e0 = enc + (size_t)0*chpx*KP;  // ywe1
    f16* e1 = enc + (size_t)1*chpx*KP;  // ywe2
    f16* e2 = enc + (size_t)2*chpx*KP;  // ywfy1
    f16* e3 = enc + (size_t)3*chpx*KP;  // ywiy1
    f16* e4 = enc + (size_t)4*chpx*KP;  // ywfy2
    f16* e5 = enc + (size_t)5*chpx*KP;  // ywiy2

    for (int c = 0; c < CHN; ++c) {
        int p_off = c * chpx;
        encoder_kernel<<<EGRID, 256, 0, stream>>>(y,
            we1_w, we1_b, we2_w, we2_b, wfy1_w, wfy1_b, wiy1_w, wiy1_b,
            wfy2_w, wfy2_b, wiy2_w, wiy2_b,
            enc, cbuf, xa, p_off, chpx);

        // step2 #1 (xt1 term == 0): xa -> xb
        gate_kernel<<<GGRID, 256, 0, stream>>>(xa, wpk2, bpk2, e1, e4, e5, xb, cbuf, xb, 1, chpx);
        for (int it = 0; it < 3; ++it) {
            // step1: xb -> xa  (add term = xb)
            gate_kernel<<<GGRID, 256, 0, stream>>>(xb, wpk1, bpk1, e0, e2, e3, xb, cbuf, xa, 0, chpx);
            // step2: xa -> xb (add term = xb); last one writes final xt1
            f16* xo = (it == 2) ? (xt1full + (size_t)p_off * KP) : xb;
            gate_kernel<<<GGRID, 256, 0, stream>>>(xa, wpk2, bpk2, e1, e4, e5, xb, cbuf, xo, 0, chpx);
        }
    }

    conv3_kernel<<<568*3, 256, 0, stream>>>(xt1full, w1p, line_b1, h1);
    gemm128_kernel<<<((NP2 + 127)/128) * 4, 256, 0, stream>>>(h1, w2p, line_b2, h2);
    final_dot_kernel<<<(NP2 + 255)/256, 256, 0, stream>>>(h2, line_w3, line_b3, out);
}